// Round 2
// baseline (423.127 us; speedup 1.0000x reference)
//
#include <hip/hip_runtime.h>

// rFFT-512, one wave per row. Round 2: register-resident complex-256 FFT.
//
// Layout: packed z[n] = x[2n] + i*x[2n+1], n = 0..255. Lane l holds positions
// p = l + 64q (q = 0..3) in registers. DIF radix-2, natural in, bit-rev out:
//   - h=128, h=64: lane-local butterflies (register math only)
//   - h=32..1:     __shfl_xor(v, h) butterflies (ds_swizzle, no addresses,
//                  no barriers, no LDS traffic)
// One LDS round-trip at the end: scatter by rev8(p) (XOR-swizzled n^(n>>4)
// to hit the 4-way b64 bank minimum), then the rfft untangle reads Z[k] and
// Z[256-k] in natural order and stores k = 0..256.
//
// Twiddles via hardware v_cos/v_sin (argument in REVOLUTIONS; all angles are
// j/(2h) in [0, 0.5) with small integer j -> no range reduction).

#define NFFT 512
#define NH 256
#define NRFFT 257
#define RPB 4          // rows (waves) per block

__device__ __forceinline__ float cosr(float t) { return __builtin_amdgcn_cosf(t); }
__device__ __forceinline__ float sinr(float t) { return __builtin_amdgcn_sinf(t); }

// bijective involution on 0..255 spreading high bits into the bank bits
__device__ __forceinline__ int swz(int n) { return n ^ (n >> 4); }

__device__ __forceinline__ void wave_lds_fence() {
    asm volatile("s_waitcnt lgkmcnt(0)" ::: "memory");
}

__global__ __launch_bounds__(256) void rfft512_kernel(const float* __restrict__ x,
                                                      float* __restrict__ out_re,
                                                      float* __restrict__ out_im,
                                                      int nrows) {
    __shared__ float2 lds[RPB][NH];

    const int lane = threadIdx.x & 63;
    const int wid  = threadIdx.x >> 6;
    const int row  = blockIdx.x * RPB + wid;
    if (row >= nrows) return;   // wave-uniform; no block-wide barriers anywhere

    // ---- load: cyclic layout, 4 coalesced dwordx2 per lane
    const float2* x2 = reinterpret_cast<const float2*>(x + (size_t)row * NFFT);
    float2 v0 = x2[lane];
    float2 v1 = x2[lane + 64];
    float2 v2 = x2[lane + 128];
    float2 v3 = x2[lane + 192];

    // ---- stage h=128 (lane-local): pairs (v0,v2) j=l ; (v1,v3) j=l+64
    float w1r, w1i;   // W_256^l, reused (squared) for stage h=64
    {
        const float t = (float)lane * (1.0f / 256.0f);   // l/256 rev, < 0.25
        w1r = cosr(t); w1i = -sinr(t);                   // e^{-2pi i l/256}
        float dx = v0.x - v2.x, dy = v0.y - v2.y;
        v0.x += v2.x; v0.y += v2.y;
        v2.x = dx * w1r - dy * w1i; v2.y = dx * w1i + dy * w1r;
        // W_256^{l+64} = W_256^l * (-i) = (w1i, -w1r)
        const float ur = w1i, ui = -w1r;
        dx = v1.x - v3.x; dy = v1.y - v3.y;
        v1.x += v3.x; v1.y += v3.y;
        v3.x = dx * ur - dy * ui; v3.y = dx * ui + dy * ur;
    }

    // ---- stage h=64 (lane-local): pairs (v0,v1) and (v2,v3), twiddle W_128^l = (W_256^l)^2
    {
        const float wr = w1r * w1r - w1i * w1i;
        const float wi = 2.0f * w1r * w1i;
        float dx = v0.x - v1.x, dy = v0.y - v1.y;
        v0.x += v1.x; v0.y += v1.y;
        v1.x = dx * wr - dy * wi; v1.y = dx * wi + dy * wr;
        dx = v2.x - v3.x; dy = v2.y - v3.y;
        v2.x += v3.x; v2.y += v3.y;
        v3.x = dx * wr - dy * wi; v3.y = dx * wi + dy * wr;
    }

    // ---- stages h=32..2: cross-lane shfl_xor butterflies
    // pair (p, p+h) <-> lanes (l, l^h), j = l & (h-1), twiddle W_{2h}^j.
    // lo lane keeps a+b; hi lane keeps (a-b)*W with a = received value.
    #pragma unroll
    for (int h = 32; h >= 2; h >>= 1) {
        const float t = (float)(lane & (h - 1)) * (0.5f / (float)h);  // j/(2h) rev
        const float wr = cosr(t), wi = -sinr(t);
        const bool hi = (lane & h) != 0;
        auto bfly = [&](float2& v) {
            const float rx = __shfl_xor(v.x, h);
            const float ry = __shfl_xor(v.y, h);
            const float ux = v.x + rx, uy = v.y + ry;
            const float dx = rx - v.x, dy = ry - v.y;   // a-b on hi lanes
            const float tx = dx * wr - dy * wi;
            const float ty = dx * wi + dy * wr;
            v.x = hi ? tx : ux;
            v.y = hi ? ty : uy;
        };
        bfly(v0); bfly(v1); bfly(v2); bfly(v3);
    }

    // ---- stage h=1: twiddle = 1
    {
        const bool hi = (lane & 1) != 0;
        auto bfly1 = [&](float2& v) {
            const float rx = __shfl_xor(v.x, 1);
            const float ry = __shfl_xor(v.y, 1);
            const float ux = v.x + rx, uy = v.y + ry;
            const float dx = rx - v.x, dy = ry - v.y;
            v.x = hi ? dx : ux;
            v.y = hi ? dy : uy;
        };
        bfly1(v0); bfly1(v1); bfly1(v2); bfly1(v3);
    }

    // ---- scatter to LDS in natural order: position p holds Z[rev8(p)];
    // rev8(l + 64q) = 4*rev6(l) + rev2(q); rev2: 0->0, 1->2, 2->1, 3->3
    {
        const int r6 = (int)(__brev((unsigned)lane) >> 26);
        float2* L = lds[wid];
        const int base = 4 * r6;
        L[swz(base + 0)] = v0;
        L[swz(base + 2)] = v1;
        L[swz(base + 1)] = v2;
        L[swz(base + 3)] = v3;
    }
    wave_lds_fence();

    // ---- untangle packed real FFT and store k = 0..256
    {
        const float2* L = lds[wid];
        const float INV512 = 0.001953125f;  // 1/512
        float* orr = out_re + (size_t)row * NRFFT;
        float* oir = out_im + (size_t)row * NRFFT;
        #pragma unroll
        for (int kk = 0; kk < 4; ++kk) {
            const int k = lane + kk * 64;
            if (k == 0) {
                const float2 z0 = L[swz(0)];
                orr[0]   = z0.x + z0.y;  oir[0]   = 0.0f;
                orr[256] = z0.x - z0.y;  oir[256] = 0.0f;
            } else {
                const float2 zk = L[swz(k)];
                const float2 zm = L[swz(256 - k)];
                const float ze_re = 0.5f * (zk.x + zm.x);
                const float ze_im = 0.5f * (zk.y - zm.y);
                const float zo_re = 0.5f * (zk.y + zm.y);
                const float zo_im = -0.5f * (zk.x - zm.x);
                const float t = (float)k * INV512;          // k/512 rev, <= 0.498
                const float c =  cosr(t);
                const float s = -sinr(t);                   // e^{-2pi i k/512}
                orr[k] = ze_re + c * zo_re - s * zo_im;
                oir[k] = ze_im + c * zo_im + s * zo_re;
            }
        }
    }
}

extern "C" void kernel_launch(void* const* d_in, const int* in_sizes, int n_in,
                              void* d_out, int out_size, void* d_ws, size_t ws_size,
                              hipStream_t stream) {
    const float* x = (const float*)d_in[0];
    // d_in[1]/d_in[2] (m_real/m_imag) unused: twiddles computed analytically.
    float* out = (float*)d_out;
    const int nrows = in_sizes[0] / NFFT;            // 32*4000 = 128000
    float* out_re = out;
    float* out_im = out + (size_t)nrows * NRFFT;     // outputs concatenated flat
    const int blocks = (nrows + RPB - 1) / RPB;      // 32000
    rfft512_kernel<<<blocks, 256, 0, stream>>>(x, out_re, out_im, nrows);
}